// Round 16
// baseline (1039.683 us; speedup 1.0000x reference)
//
#include <hip/hip_runtime.h>

// DKVMN forward, round 30 — row-granular skip from full ballot.
// R29 green: total 966, kS 791 (VALU-issue ~481 us). Decomposition: 4-row
// group skip computes ~6.24 rows/wave-step but only ~1.87 are hot (w>EPSW) —
// 3.3x gratuitous ROWOPs. kW's ballot already has per-row bits; R29's u16
// group compression threw them away. R30: kW stores the FULL 64-bit ballot
// per (c,wave) (hball u64[513][8], 32 KB); kS extracts its 16 row-bits
// (wave-uniform u32 LDS read + readfirstlane -> SGPR) and guards EACH row's
// ROWOP with a scalar bit test (s_cbranch, SALU pipe — zero VALU). All reads
// (4x w b128 + e/a) are issued UNCONDITIONALLY up front so hot-row FMAs hit
// registers, not fresh 120-cyc LDS chains. Per-step VALU ~92 -> ~35 instr.
// Same per-row predicate w>EPSW -> skip set covered by the R23 error bound
// (which assumed all sub-EPSW rows skipped). WRITE_SIZE=131072 is the spill
// tripwire. kM/kG byte-identical to R29.
//   kW: wtab[513][512] fp32 + hball[513][8] u64   kG: etab/atab fp32
//   kS: ring-staged, s_racc dbuf, 1 barrier/4 steps, row-mask skip.
//   kM: lane=p, readfirstlane-scalar weights, odd-stride b32 LDS.
// ws = 3.2 MB + 64 KB + 128 MiB.

#define B_ 256
#define T_ 512
#define N_ 512
#define DK_ 64
#define DV_ 256
#define S_ 64
#define NP_ (B_ * T_)
#define NCID 513
#define NIID 1025
#define EPSW 1e-6f

typedef _Float16 h16;
typedef __attribute__((ext_vector_type(4))) _Float16 half4;
typedef unsigned int u32;
typedef unsigned long long u64;

__device__ __forceinline__ float dot4(float4 a, float4 b) {
  return a.x * b.x + a.y * b.y + a.z * b.z + a.w * b.w;
}
__device__ __forceinline__ float4 h2f(half4 h) {
  return make_float4((float)h.x, (float)h.y, (float)h.z, (float)h.w);
}
__device__ __forceinline__ half4 f2h(float4 f) {
  half4 h;
  h.x = (h16)f.x; h.y = (h16)f.y; h.z = (h16)f.z; h.w = (h16)f.w;
  return h;
}

// ============ kW: wtab[c][n] + hball[c][wave], 513 blocks ==================
__global__ __launch_bounds__(512) void kW(const float* __restrict__ Kmem,
                                          const float* __restrict__ cemb,
                                          float* __restrict__ wtab,
                                          u64* __restrict__ hball) {
  __shared__ float s_q[DK_];
  __shared__ float s_red[16];
  const int tid = threadIdx.x, c = blockIdx.x;
  if (tid < DK_) s_q[tid] = c ? cemb[c * DK_ + tid] : 0.f;
  __syncthreads();
  const int n = tid;
  const float4* kr = (const float4*)(Kmem + n * DK_);
  float acc = 0.f;
#pragma unroll
  for (int kk = 0; kk < DK_ / 4; ++kk) acc += dot4(kr[kk], *(const float4*)&s_q[kk * 4]);
  const int lane = tid & 63, wid = tid >> 6;
  float mx = acc;
  for (int off = 32; off; off >>= 1) mx = fmaxf(mx, __shfl_xor(mx, off, 64));
  if (lane == 0) s_red[wid] = mx;
  __syncthreads();
  float gmx = s_red[0];
#pragma unroll
  for (int i = 1; i < 8; ++i) gmx = fmaxf(gmx, s_red[i]);
  const float e = expf(acc - gmx);
  float sum = e;
  for (int off = 32; off; off >>= 1) sum += __shfl_xor(sum, off, 64);
  if (lane == 0) s_red[8 + wid] = sum;
  __syncthreads();
  float gs = 0.f;
#pragma unroll
  for (int i = 0; i < 8; ++i) gs += s_red[8 + i];
  const float w = e / gs;
  wtab[c * N_ + n] = w;
  // full per-row hot ballot: bit l of hball[c*8+wid] = (w of row wid*64+l > EPSW)
  const u64 bal = __ballot(w > EPSW);
  if (lane == 0) hball[c * 8 + wid] = bal;
}

// ============ kG: etab/atab[id][d], 129 blocks x 8 ids =====================
__global__ __launch_bounds__(512) void kG(const float* __restrict__ iemb,
                                          const float* __restrict__ We,
                                          const float* __restrict__ be,
                                          const float* __restrict__ Wa,
                                          const float* __restrict__ ba,
                                          float* __restrict__ etab,
                                          float* __restrict__ atab) {
  __shared__ float s_v[8 * DV_];
  const int tid = threadIdx.x, bi = blockIdx.x;
  {
    const int j = tid >> 6, c4 = tid & 63;
    const int id = bi * 8 + j;
    float4 v = make_float4(0.f, 0.f, 0.f, 0.f);
    if (id >= 1 && id < NIID) v = ((const float4*)iemb)[(size_t)id * 64 + c4];
    *(float4*)&s_v[j * DV_ + c4 * 4] = v;
  }
  __syncthreads();
  const int gate = tid >> 8, d = tid & 255;
  const float4* wr = (const float4*)((gate ? Wa : We) + d * DV_);
  float acc[8];
#pragma unroll
  for (int j = 0; j < 8; ++j) acc[j] = 0.f;
  for (int kk = 0; kk < DV_ / 4; ++kk) {
    const float4 w4 = wr[kk];
#pragma unroll
    for (int j = 0; j < 8; ++j) acc[j] += dot4(w4, *(const float4*)&s_v[j * DV_ + kk * 4]);
  }
  const float bias = gate ? ba[d] : be[d];
#pragma unroll
  for (int j = 0; j < 8; ++j) {
    const int id = bi * 8 + j;
    if (id < NIID) {
      if (gate) atab[(size_t)id * DV_ + d] = tanhf(acc[j] + bias);
      else      etab[(size_t)id * DV_ + d] = 1.f / (1.f + expf(-(acc[j] + bias)));
    }
  }
}

// ============ kS: ring-staged row-mask recurrence, 512 x 1024 ==============
#define ROWOP(mr, wsel)                                   \
  do {                                                    \
    const float w_ = (wsel);                              \
    racc.x = fmaf(w_, mr.x, racc.x);                      \
    racc.y = fmaf(w_, mr.y, racc.y);                      \
    racc.z = fmaf(w_, mr.z, racc.z);                      \
    racc.w = fmaf(w_, mr.w, racc.w);                      \
    mr.x = fmaf(-w_, fmaf(e4.x, mr.x, -a4.x), mr.x);      \
    mr.y = fmaf(-w_, fmaf(e4.y, mr.y, -a4.y), mr.y);      \
    mr.z = fmaf(-w_, fmaf(e4.z, mr.z, -a4.z), mr.z);      \
    mr.w = fmaf(-w_, fmaf(e4.w, mr.w, -a4.w), mr.w);      \
  } while (0)

__global__ __launch_bounds__(1024)
__attribute__((amdgpu_waves_per_eu(4, 4))) void kS(
    const int* __restrict__ concepts, const int* __restrict__ inter,
    const float* __restrict__ Vmem, const float* __restrict__ wtab,
    const float* __restrict__ etab, const float* __restrict__ atab,
    const u64* __restrict__ hball, h16* __restrict__ rpart) {
  __shared__ float s_w[8][DV_];            // 8 KB: ring of 8 t-rows
  __shared__ float s_e[8][DV_];            // 8 KB
  __shared__ float s_a[8][DV_];            // 8 KB
  __shared__ __align__(16) u32 s_mask[8][16];  // 512 B: per-slot row ballots
  __shared__ float s_racc[2][4][16][DV_];  // 128 KB: double-buffered windows
  const int tid = threadIdx.x, bx = blockIdx.x;
  const int b = bx >> 1, ch = bx & 1;
  const int lane = tid & 63, wv = tid >> 6;  // 16 waves
  const int row0 = ch * 256 + __builtin_amdgcn_readfirstlane(wv * 16);
  // this wave's 16 row-bits: u32 word + shift within the ballot
  const int midx = (ch * 4 + (wv >> 2)) * 2 + ((wv >> 1) & 1);
  const int mshift = (wv & 1) * 16;
  float4 m0, m1, m2, m3, m4, m5, m6, m7, m8, m9, m10, m11, m12, m13, m14, m15;
  {
    const float4* vm4 = (const float4*)Vmem + (size_t)row0 * 64 + lane;
    m0 = vm4[0 * 64];   m1 = vm4[1 * 64];   m2 = vm4[2 * 64];   m3 = vm4[3 * 64];
    m4 = vm4[4 * 64];   m5 = vm4[5 * 64];   m6 = vm4[6 * 64];   m7 = vm4[7 * 64];
    m8 = vm4[8 * 64];   m9 = vm4[9 * 64];   m10 = vm4[10 * 64]; m11 = vm4[11 * 64];
    m12 = vm4[12 * 64]; m13 = vm4[13 * 64]; m14 = vm4[14 * 64]; m15 = vm4[15 * 64];
  }
  const int* cb = concepts + b * T_;
  const int* ib = inter + b * T_;
  const float4* wtab4 = (const float4*)wtab;
  const float4* etab4 = (const float4*)etab;
  const float4* atab4 = (const float4*)atab;
  const u32* hb32 = (const u32*)hball;
  h16* rp = rpart + (size_t)ch * NP_ * DV_ + (size_t)b * T_ * DV_;

  // stage 4 t-rows (w/e/a + ballot) into ring slots (tb..tb+3)&7.
  auto stage4 = [&](int tb, int toff) {
    const int idx = tid - toff;
    if (idx >= 0 && idx < 768) {
      const int r = idx / 192, q = idx % 192;
      const int arr = q >> 6, c4 = q & 63;
      const int t = tb + r, sl = t & 7;
      if (arr == 0) {
        *(float4*)&s_w[sl][c4 * 4] = wtab4[(size_t)cb[t] * 128 + ch * 64 + c4];
        if (c4 < 4)
          *(uint4*)&s_mask[sl][c4 * 4] =
              *(const uint4*)(hb32 + (size_t)cb[t] * 16 + c4 * 4);
      } else if (arr == 1) {
        *(float4*)&s_e[sl][c4 * 4] = etab4[(size_t)ib[t] * 64 + c4];
      } else {
        *(float4*)&s_a[sl][c4 * 4] = atab4[(size_t)ib[t] * 64 + c4];
      }
    }
  };

  stage4(0, 0);
  __syncthreads();

  for (int t0 = 0; t0 < T_; t0 += 4) {
    const int win = (t0 >> 2) & 1;
#pragma unroll 1  // CAP PRESSURE: one step's LDS reads live at a time
    for (int j = 0; j < 4; ++j) {
      const int sl = (t0 + j) & 7;
      // unconditional reads up front — latency overlapped, FMAs hit registers
      const float* wrow = &s_w[sl][wv * 16];
      const float4 wq0 = *(const float4*)(wrow + 0);
      const float4 wq1 = *(const float4*)(wrow + 4);
      const float4 wq2 = *(const float4*)(wrow + 8);
      const float4 wq3 = *(const float4*)(wrow + 12);
      const float4 e4 = *(const float4*)&s_e[sl][lane * 4];
      const float4 a4 = *(const float4*)&s_a[sl][lane * 4];
      const u32 bits =
          (__builtin_amdgcn_readfirstlane(s_mask[sl][midx]) >> mshift) & 0xFFFFu;
      float4 racc = make_float4(0.f, 0.f, 0.f, 0.f);
      if (bits) {  // per-row scalar-branch skip (SALU, zero VALU cost)
        if (bits & 0x0001u) ROWOP(m0, wq0.x);
        if (bits & 0x0002u) ROWOP(m1, wq0.y);
        if (bits & 0x0004u) ROWOP(m2, wq0.z);
        if (bits & 0x0008u) ROWOP(m3, wq0.w);
        if (bits & 0x0010u) ROWOP(m4, wq1.x);
        if (bits & 0x0020u) ROWOP(m5, wq1.y);
        if (bits & 0x0040u) ROWOP(m6, wq1.z);
        if (bits & 0x0080u) ROWOP(m7, wq1.w);
        if (bits & 0x0100u) ROWOP(m8, wq2.x);
        if (bits & 0x0200u) ROWOP(m9, wq2.y);
        if (bits & 0x0400u) ROWOP(m10, wq2.z);
        if (bits & 0x0800u) ROWOP(m11, wq2.w);
        if (bits & 0x1000u) ROWOP(m12, wq3.x);
        if (bits & 0x2000u) ROWOP(m13, wq3.y);
        if (bits & 0x4000u) ROWOP(m14, wq3.z);
        if (bits & 0x8000u) ROWOP(m15, wq3.w);
      }
      *(float4*)&s_racc[win][j][wv][lane * 4] = racc;
    }
    if (t0 + 4 < T_) stage4(t0 + 4, 256);
    if (t0 > 0 && tid < 256) {
      const int j = tid >> 6, l = tid & 63;
      float4 acc = make_float4(0.f, 0.f, 0.f, 0.f);
#pragma unroll 4
      for (int w2 = 0; w2 < 16; ++w2) {
        const float4 v = *(const float4*)&s_racc[win ^ 1][j][w2][l * 4];
        acc.x += v.x; acc.y += v.y; acc.z += v.z; acc.w += v.w;
      }
      *(half4*)(rp + (size_t)(t0 - 4 + j) * DV_ + l * 4) = f2h(acc);
    }
    __syncthreads();
  }
  if (tid < 256) {
    const int buf = ((T_ - 4) >> 2) & 1;
    const int j = tid >> 6, l = tid & 63;
    float4 acc = make_float4(0.f, 0.f, 0.f, 0.f);
#pragma unroll 4
    for (int w2 = 0; w2 < 16; ++w2) {
      const float4 v = *(const float4*)&s_racc[buf][j][w2][l * 4];
      acc.x += v.x; acc.y += v.y; acc.z += v.z; acc.w += v.w;
    }
    *(half4*)(rp + (size_t)(T_ - 4 + j) * DV_ + l * 4) = f2h(acc);
  }
}

// ============ kM: MLP head, 2048 blocks x 1024 thr, lane=p (R28-exact) =====
#define MP_ 64
#define SF_ 321  // s_f dword stride (odd -> bank-conflict-free b32)
#define SH_ 65   // s_h1 dword stride (odd)
#define SR_ 17   // s_red dword stride (odd)
__global__ __launch_bounds__(1024)
__attribute__((amdgpu_waves_per_eu(4, 4))) void kM(
    const int* __restrict__ concepts, const float* __restrict__ cemb,
    const h16* __restrict__ rpart, const float* __restrict__ W1,
    const float* __restrict__ b1, const float* __restrict__ W2,
    const float* __restrict__ b2, const float* __restrict__ W3,
    const float* __restrict__ b3, float* __restrict__ out) {
  __shared__ float s_f[MP_][SF_];   // 82.2 KB: f = [r(256) | q(64)] fp32
  __shared__ float s_h1[MP_][SH_];  // 16.6 KB
  __shared__ float s_red[MP_][SR_]; // 4.4 KB
  __shared__ int s_c[MP_];
  const int tid = threadIdx.x, g = blockIdx.x;
  const int lane = tid & 63, wv = tid >> 6;  // 16 waves; lane = sample p
  if (tid < MP_) s_c[tid] = concepts[g * MP_ + tid];
  __syncthreads();
  {
    const half4* p0 = (const half4*)rpart;
    const half4* p1 = p0 + (size_t)NP_ * 64;
#pragma unroll
    for (int i = 0; i < 4; ++i) {
      const int idx = tid + i * 1024, p = idx >> 6, c4 = idx & 63;
      const size_t off = (size_t)(g * MP_ + p) * 64 + c4;
      const float4 v0 = h2f(p0[off]);
      const float4 v1 = h2f(p1[off]);
      s_f[p][c4 * 4 + 0] = v0.x + v1.x;
      s_f[p][c4 * 4 + 1] = v0.y + v1.y;
      s_f[p][c4 * 4 + 2] = v0.z + v1.z;
      s_f[p][c4 * 4 + 3] = v0.w + v1.w;
    }
    const float4* ce4 = (const float4*)cemb;
    const float4 z = make_float4(0.f, 0.f, 0.f, 0.f);
    const int p = tid >> 4, k4 = tid & 15;
    const int c = s_c[p];
    const float4 q = c ? ce4[c * 16 + k4] : z;
    s_f[p][DV_ + k4 * 4 + 0] = q.x;
    s_f[p][DV_ + k4 * 4 + 1] = q.y;
    s_f[p][DV_ + k4 * 4 + 2] = q.z;
    s_f[p][DV_ + k4 * 4 + 3] = q.w;
  }
  __syncthreads();
  // ---- layer 1: h1[p][j] = relu(b1[j] + sum_k W1[j][k] f[p][k]) ----
  {
    const int j0 = __builtin_amdgcn_readfirstlane(wv * 4);  // FORCE scalar
    const float* W1r0 = W1 + (size_t)(j0 + 0) * 320;
    const float* W1r1 = W1 + (size_t)(j0 + 1) * 320;
    const float* W1r2 = W1 + (size_t)(j0 + 2) * 320;
    const float* W1r3 = W1 + (size_t)(j0 + 3) * 320;
    float a0 = b1[j0 + 0], a1 = b1[j0 + 1], a2 = b1[j0 + 2], a3 = b1[j0 + 3];
#pragma unroll 4
    for (int k4 = 0; k4 < 80; ++k4) {
      const float4 w0 = *(const float4*)(W1r0 + k4 * 4);  // s_load (uniform)
      const float4 w1 = *(const float4*)(W1r1 + k4 * 4);
      const float4 w2 = *(const float4*)(W1r2 + k4 * 4);
      const float4 w3 = *(const float4*)(W1r3 + k4 * 4);
      const float f0 = s_f[lane][k4 * 4 + 0];  // conflict-free b32
      const float f1 = s_f[lane][k4 * 4 + 1];
      const float f2 = s_f[lane][k4 * 4 + 2];
      const float f3 = s_f[lane][k4 * 4 + 3];
      a0 = fmaf(w0.x, f0, fmaf(w0.y, f1, fmaf(w0.z, f2, fmaf(w0.w, f3, a0))));
      a1 = fmaf(w1.x, f0, fmaf(w1.y, f1, fmaf(w1.z, f2, fmaf(w1.w, f3, a1))));
      a2 = fmaf(w2.x, f0, fmaf(w2.y, f1, fmaf(w2.z, f2, fmaf(w2.w, f3, a2))));
      a3 = fmaf(w3.x, f0, fmaf(w3.y, f1, fmaf(w3.z, f2, fmaf(w3.w, f3, a3))));
    }
    s_h1[lane][j0 + 0] = fmaxf(a0, 0.f);
    s_h1[lane][j0 + 1] = fmaxf(a1, 0.f);
    s_h1[lane][j0 + 2] = fmaxf(a2, 0.f);
    s_h1[lane][j0 + 3] = fmaxf(a3, 0.f);
  }
  __syncthreads();
  // ---- layer 2 + W3 partial: wave handles j2 = 4wv..4wv+3 ----
  {
    const int j0 = __builtin_amdgcn_readfirstlane(wv * 4);  // FORCE scalar
    const float* W2r0 = W2 + (size_t)(j0 + 0) * 64;
    const float* W2r1 = W2 + (size_t)(j0 + 1) * 64;
    const float* W2r2 = W2 + (size_t)(j0 + 2) * 64;
    const float* W2r3 = W2 + (size_t)(j0 + 3) * 64;
    float a0 = b2[j0 + 0], a1 = b2[j0 + 1], a2 = b2[j0 + 2], a3 = b2[j0 + 3];
#pragma unroll 4
    for (int k4 = 0; k4 < 16; ++k4) {
      const float4 w0 = *(const float4*)(W2r0 + k4 * 4);
      const float4 w1 = *(const float4*)(W2r1 + k4 * 4);
      const float4 w2 = *(const float4*)(W2r2 + k4 * 4);
      const float4 w3 = *(const float4*)(W2r3 + k4 * 4);
      const float h0 = s_h1[lane][k4 * 4 + 0];
      const float h1v = s_h1[lane][k4 * 4 + 1];
      const float h2v = s_h1[lane][k4 * 4 + 2];
      const float h3 = s_h1[lane][k4 * 4 + 3];
      a0 = fmaf(w0.x, h0, fmaf(w0.y, h1v, fmaf(w0.z, h2v, fmaf(w0.w, h3, a0))));
      a1 = fmaf(w1.x, h0, fmaf(w1.y, h1v, fmaf(w1.z, h2v, fmaf(w1.w, h3, a1))));
      a2 = fmaf(w2.x, h0, fmaf(w2.y, h1v, fmaf(w2.z, h2v, fmaf(w2.w, h3, a2))));
      a3 = fmaf(w3.x, h0, fmaf(w3.y, h1v, fmaf(w3.z, h2v, fmaf(w3.w, h3, a3))));
    }
    const float p3 = fmaxf(a0, 0.f) * W3[j0 + 0] + fmaxf(a1, 0.f) * W3[j0 + 1] +
                     fmaxf(a2, 0.f) * W3[j0 + 2] + fmaxf(a3, 0.f) * W3[j0 + 3];
    s_red[lane][wv] = p3;
  }
  __syncthreads();
  if (wv == 0) {
    float s = b3[0];
#pragma unroll
    for (int w = 0; w < 16; ++w) s += s_red[lane][w];
    out[g * MP_ + lane] = 1.f / (1.f + expf(-s));
  }
}

extern "C" void kernel_launch(void* const* d_in, const int* in_sizes, int n_in,
                              void* d_out, int out_size, void* d_ws, size_t ws_size,
                              hipStream_t stream) {
  const int* concepts = (const int*)d_in[0];
  const int* interactions = (const int*)d_in[1];
  const float* Kmem = (const float*)d_in[2];
  const float* Vmem = (const float*)d_in[3];
  const float* cemb = (const float*)d_in[4];
  const float* iemb = (const float*)d_in[5];
  const float* We = (const float*)d_in[6];
  const float* be = (const float*)d_in[7];
  const float* Wa = (const float*)d_in[8];
  const float* ba = (const float*)d_in[9];
  const float* W1 = (const float*)d_in[10];
  const float* b1 = (const float*)d_in[11];
  const float* W2 = (const float*)d_in[12];
  const float* b2 = (const float*)d_in[13];
  const float* W3 = (const float*)d_in[14];
  const float* b3 = (const float*)d_in[15];
  float* out = (float*)d_out;

  const size_t sz_w = (size_t)NCID * N_ * 4;
  const size_t sz_e = (size_t)NIID * DV_ * 4;
  float* wtab = (float*)d_ws;
  float* etab = (float*)((char*)d_ws + sz_w);
  float* atab = (float*)((char*)d_ws + sz_w + sz_e);
  u64* hball = (u64*)((char*)d_ws + sz_w + 2 * sz_e);            // 32.8 KB
  h16* rpart = (h16*)((char*)d_ws + sz_w + 2 * sz_e + 65536);    // 2 x 64 MiB

  kW<<<dim3(NCID), dim3(512), 0, stream>>>(Kmem, cemb, wtab, hball);
  kG<<<dim3((NIID + 7) / 8), dim3(512), 0, stream>>>(iemb, We, be, Wa, ba, etab, atab);
  kS<<<dim3(B_ * 2), dim3(1024), 0, stream>>>(concepts, interactions, Vmem,
                                              wtab, etab, atab, hball, rpart);
  kM<<<dim3(NP_ / MP_), dim3(1024), 0, stream>>>(concepts, cemb, rpart,
                                                 W1, b1, W2, b2, W3, b3, out);
}

// Round 17
// 974.914 us; speedup vs baseline: 1.0664x; 1.0664x over previous
//
#include <hip/hip_runtime.h>

// DKVMN forward, round 31 — R29 group-skip + R30's hoisted reads (hybrid).
// R30 post-mortem: row-granular skip REGRESSED (791->828) — 16 scalar-branch
// blocks/step cost more than the ~4.4 cold-row ROWOPs they saved (taken-branch
// fetch bubbles + lost scheduling). VALUBusy fell 60.8->50.2 but stall grew.
// Lesson: skip granularity optimum on CDNA = 4-row groups (48-instr body),
// not rows (12). R30's one validated piece: unconditional hoisted LDS reads
// (wq/e/a) are allocator-safe (VGPR 64, no spill) and take the 120-cyc
// ds_read latency off the branch-body critical path. R31 = R29 exactly, plus
// that hoist. Skip set bit-identical to R29 (same u16 group masks from kW).
//   kW: wtab[513][512] fp32 + hmask[513][8] u16   kG: etab/atab fp32
//   kS: ring-staged, s_racc dbuf, 1 barrier/4 steps, 4-group scalar skip,
//       hoisted reads; named m0..m15; unroll-1 j-loop; tid<256 f4 drain.
//   kM: lane=p, readfirstlane-scalar weights, odd-stride b32 LDS (R28-exact).
// ws = 3.2 MB + 16 KB + 128 MiB. WRITE_SIZE=131072 is the spill tripwire.

#define B_ 256
#define T_ 512
#define N_ 512
#define DK_ 64
#define DV_ 256
#define S_ 64
#define NP_ (B_ * T_)
#define NCID 513
#define NIID 1025
#define EPSW 1e-6f

typedef _Float16 h16;
typedef __attribute__((ext_vector_type(4))) _Float16 half4;
typedef unsigned int u32;
typedef unsigned short u16;

__device__ __forceinline__ float dot4(float4 a, float4 b) {
  return a.x * b.x + a.y * b.y + a.z * b.z + a.w * b.w;
}
__device__ __forceinline__ float4 h2f(half4 h) {
  return make_float4((float)h.x, (float)h.y, (float)h.z, (float)h.w);
}
__device__ __forceinline__ half4 f2h(float4 f) {
  half4 h;
  h.x = (h16)f.x; h.y = (h16)f.y; h.z = (h16)f.z; h.w = (h16)f.w;
  return h;
}

// ============ kW: wtab[c][n] + hmask[c][wave], 513 blocks ==================
__global__ __launch_bounds__(512) void kW(const float* __restrict__ Kmem,
                                          const float* __restrict__ cemb,
                                          float* __restrict__ wtab,
                                          u16* __restrict__ hmask) {
  __shared__ float s_q[DK_];
  __shared__ float s_red[16];
  const int tid = threadIdx.x, c = blockIdx.x;
  if (tid < DK_) s_q[tid] = c ? cemb[c * DK_ + tid] : 0.f;
  __syncthreads();
  const int n = tid;
  const float4* kr = (const float4*)(Kmem + n * DK_);
  float acc = 0.f;
#pragma unroll
  for (int kk = 0; kk < DK_ / 4; ++kk) acc += dot4(kr[kk], *(const float4*)&s_q[kk * 4]);
  const int lane = tid & 63, wid = tid >> 6;
  float mx = acc;
  for (int off = 32; off; off >>= 1) mx = fmaxf(mx, __shfl_xor(mx, off, 64));
  if (lane == 0) s_red[wid] = mx;
  __syncthreads();
  float gmx = s_red[0];
#pragma unroll
  for (int i = 1; i < 8; ++i) gmx = fmaxf(gmx, s_red[i]);
  const float e = expf(acc - gmx);
  float sum = e;
  for (int off = 32; off; off >>= 1) sum += __shfl_xor(sum, off, 64);
  if (lane == 0) s_red[8 + wid] = sum;
  __syncthreads();
  float gs = 0.f;
#pragma unroll
  for (int i = 0; i < 8; ++i) gs += s_red[8 + i];
  const float w = e / gs;
  wtab[c * N_ + n] = w;
  // hot-group mask: bit i of hmask[c*8+wid] = OR over 4 rows of (w > EPSW).
  const unsigned long long bal = __ballot(w > EPSW);
  if (lane == 0) {
    u16 mm = 0;
#pragma unroll
    for (int i = 0; i < 16; ++i)
      if ((bal >> (4 * i)) & 0xFull) mm |= (u16)(1u << i);
    hmask[c * 8 + wid] = mm;
  }
}

// ============ kG: etab/atab[id][d], 129 blocks x 8 ids =====================
__global__ __launch_bounds__(512) void kG(const float* __restrict__ iemb,
                                          const float* __restrict__ We,
                                          const float* __restrict__ be,
                                          const float* __restrict__ Wa,
                                          const float* __restrict__ ba,
                                          float* __restrict__ etab,
                                          float* __restrict__ atab) {
  __shared__ float s_v[8 * DV_];
  const int tid = threadIdx.x, bi = blockIdx.x;
  {
    const int j = tid >> 6, c4 = tid & 63;
    const int id = bi * 8 + j;
    float4 v = make_float4(0.f, 0.f, 0.f, 0.f);
    if (id >= 1 && id < NIID) v = ((const float4*)iemb)[(size_t)id * 64 + c4];
    *(float4*)&s_v[j * DV_ + c4 * 4] = v;
  }
  __syncthreads();
  const int gate = tid >> 8, d = tid & 255;
  const float4* wr = (const float4*)((gate ? Wa : We) + d * DV_);
  float acc[8];
#pragma unroll
  for (int j = 0; j < 8; ++j) acc[j] = 0.f;
  for (int kk = 0; kk < DV_ / 4; ++kk) {
    const float4 w4 = wr[kk];
#pragma unroll
    for (int j = 0; j < 8; ++j) acc[j] += dot4(w4, *(const float4*)&s_v[j * DV_ + kk * 4]);
  }
  const float bias = gate ? ba[d] : be[d];
#pragma unroll
  for (int j = 0; j < 8; ++j) {
    const int id = bi * 8 + j;
    if (id < NIID) {
      if (gate) atab[(size_t)id * DV_ + d] = tanhf(acc[j] + bias);
      else      etab[(size_t)id * DV_ + d] = 1.f / (1.f + expf(-(acc[j] + bias)));
    }
  }
}

// ============ kS: ring-staged mask-driven recurrence, 512 x 1024 ===========
#define ROWOP(mr, wsel)                                   \
  do {                                                    \
    const float w_ = (wsel);                              \
    racc.x = fmaf(w_, mr.x, racc.x);                      \
    racc.y = fmaf(w_, mr.y, racc.y);                      \
    racc.z = fmaf(w_, mr.z, racc.z);                      \
    racc.w = fmaf(w_, mr.w, racc.w);                      \
    mr.x = fmaf(-w_, fmaf(e4.x, mr.x, -a4.x), mr.x);      \
    mr.y = fmaf(-w_, fmaf(e4.y, mr.y, -a4.y), mr.y);      \
    mr.z = fmaf(-w_, fmaf(e4.z, mr.z, -a4.z), mr.z);      \
    mr.w = fmaf(-w_, fmaf(e4.w, mr.w, -a4.w), mr.w);      \
  } while (0)

// guarded group with PRE-LOADED wq (reads hoisted off the branch body)
#define GRPH(bitv, wq, A, B, C, D)                                        \
  if (nib & (bitv)) {                                                     \
    ROWOP(A, wq.x); ROWOP(B, wq.y); ROWOP(C, wq.z); ROWOP(D, wq.w);       \
  }

__global__ __launch_bounds__(1024)
__attribute__((amdgpu_waves_per_eu(4, 4))) void kS(
    const int* __restrict__ concepts, const int* __restrict__ inter,
    const float* __restrict__ Vmem, const float* __restrict__ wtab,
    const float* __restrict__ etab, const float* __restrict__ atab,
    const u16* __restrict__ hmask, h16* __restrict__ rpart) {
  __shared__ float s_w[8][DV_];            // 8 KB: ring of 8 t-rows
  __shared__ float s_e[8][DV_];            // 8 KB
  __shared__ float s_a[8][DV_];            // 8 KB
  __shared__ __align__(16) u16 s_mask[8][8];  // 128 B: hot-group masks
  __shared__ float s_racc[2][4][16][DV_];  // 128 KB: double-buffered windows
  const int tid = threadIdx.x, bx = blockIdx.x;
  const int b = bx >> 1, ch = bx & 1;
  const int lane = tid & 63, wv = tid >> 6;  // 16 waves
  const int row0 = ch * 256 + __builtin_amdgcn_readfirstlane(wv * 16);
  const int mword = ch * 4 + (wv >> 2);      // this wave's hmask u16 index
  const int mshift = (wv & 3) * 4;           // nibble position within it
  float4 m0, m1, m2, m3, m4, m5, m6, m7, m8, m9, m10, m11, m12, m13, m14, m15;
  {
    const float4* vm4 = (const float4*)Vmem + (size_t)row0 * 64 + lane;
    m0 = vm4[0 * 64];   m1 = vm4[1 * 64];   m2 = vm4[2 * 64];   m3 = vm4[3 * 64];
    m4 = vm4[4 * 64];   m5 = vm4[5 * 64];   m6 = vm4[6 * 64];   m7 = vm4[7 * 64];
    m8 = vm4[8 * 64];   m9 = vm4[9 * 64];   m10 = vm4[10 * 64]; m11 = vm4[11 * 64];
    m12 = vm4[12 * 64]; m13 = vm4[13 * 64]; m14 = vm4[14 * 64]; m15 = vm4[15 * 64];
  }
  const int* cb = concepts + b * T_;
  const int* ib = inter + b * T_;
  const float4* wtab4 = (const float4*)wtab;
  const float4* etab4 = (const float4*)etab;
  const float4* atab4 = (const float4*)atab;
  h16* rp = rpart + (size_t)ch * NP_ * DV_ + (size_t)b * T_ * DV_;

  // stage 4 t-rows (w/e/a + mask) into ring slots (tb..tb+3)&7; 768 threads.
  auto stage4 = [&](int tb, int toff) {
    const int idx = tid - toff;
    if (idx >= 0 && idx < 768) {
      const int r = idx / 192, q = idx % 192;
      const int arr = q >> 6, c4 = q & 63;
      const int t = tb + r, sl = t & 7;
      if (arr == 0) {
        *(float4*)&s_w[sl][c4 * 4] = wtab4[(size_t)cb[t] * 128 + ch * 64 + c4];
        if (q == 0)
          *(uint4*)&s_mask[sl][0] = *(const uint4*)(hmask + (size_t)cb[t] * 8);
      } else if (arr == 1) {
        *(float4*)&s_e[sl][c4 * 4] = etab4[(size_t)ib[t] * 64 + c4];
      } else {
        *(float4*)&s_a[sl][c4 * 4] = atab4[(size_t)ib[t] * 64 + c4];
      }
    }
  };

  stage4(0, 0);
  __syncthreads();

  for (int t0 = 0; t0 < T_; t0 += 4) {
    const int win = (t0 >> 2) & 1;
#pragma unroll 1  // CAP PRESSURE: one step's LDS reads live at a time
    for (int j = 0; j < 4; ++j) {
      const int sl = (t0 + j) & 7;
      // unconditional hoisted reads — latency overlapped, FMAs hit registers
      const float* wrow = &s_w[sl][wv * 16];
      const float4 wq0 = *(const float4*)(wrow + 0);
      const float4 wq1 = *(const float4*)(wrow + 4);
      const float4 wq2 = *(const float4*)(wrow + 8);
      const float4 wq3 = *(const float4*)(wrow + 12);
      const float4 e4 = *(const float4*)&s_e[sl][lane * 4];
      const float4 a4 = *(const float4*)&s_a[sl][lane * 4];
      const u32 nib =
          (__builtin_amdgcn_readfirstlane((u32)s_mask[sl][mword]) >> mshift) & 0xFu;
      float4 racc = make_float4(0.f, 0.f, 0.f, 0.f);
      if (nib) {  // 4-group scalar skip (proven optimum granularity)
        GRPH(1u, wq0, m0, m1, m2, m3)
        GRPH(2u, wq1, m4, m5, m6, m7)
        GRPH(4u, wq2, m8, m9, m10, m11)
        GRPH(8u, wq3, m12, m13, m14, m15)
      }
      *(float4*)&s_racc[win][j][wv][lane * 4] = racc;
    }
    if (t0 + 4 < T_) stage4(t0 + 4, 256);
    if (t0 > 0 && tid < 256) {
      const int j = tid >> 6, l = tid & 63;
      float4 acc = make_float4(0.f, 0.f, 0.f, 0.f);
#pragma unroll 4
      for (int w2 = 0; w2 < 16; ++w2) {
        const float4 v = *(const float4*)&s_racc[win ^ 1][j][w2][l * 4];
        acc.x += v.x; acc.y += v.y; acc.z += v.z; acc.w += v.w;
      }
      *(half4*)(rp + (size_t)(t0 - 4 + j) * DV_ + l * 4) = f2h(acc);
    }
    __syncthreads();
  }
  if (tid < 256) {
    const int buf = ((T_ - 4) >> 2) & 1;
    const int j = tid >> 6, l = tid & 63;
    float4 acc = make_float4(0.f, 0.f, 0.f, 0.f);
#pragma unroll 4
    for (int w2 = 0; w2 < 16; ++w2) {
      const float4 v = *(const float4*)&s_racc[buf][j][w2][l * 4];
      acc.x += v.x; acc.y += v.y; acc.z += v.z; acc.w += v.w;
    }
    *(half4*)(rp + (size_t)(T_ - 4 + j) * DV_ + l * 4) = f2h(acc);
  }
}

// ============ kM: MLP head, 2048 blocks x 1024 thr, lane=p (R28-exact) =====
#define MP_ 64
#define SF_ 321  // s_f dword stride (odd -> bank-conflict-free b32)
#define SH_ 65   // s_h1 dword stride (odd)
#define SR_ 17   // s_red dword stride (odd)
__global__ __launch_bounds__(1024)
__attribute__((amdgpu_waves_per_eu(4, 4))) void kM(
    const int* __restrict__ concepts, const float* __restrict__ cemb,
    const h16* __restrict__ rpart, const float* __restrict__ W1,
    const float* __restrict__ b1, const float* __restrict__ W2,
    const float* __restrict__ b2, const float* __restrict__ W3,
    const float* __restrict__ b3, float* __restrict__ out) {
  __shared__ float s_f[MP_][SF_];   // 82.2 KB: f = [r(256) | q(64)] fp32
  __shared__ float s_h1[MP_][SH_];  // 16.6 KB
  __shared__ float s_red[MP_][SR_]; // 4.4 KB
  __shared__ int s_c[MP_];
  const int tid = threadIdx.x, g = blockIdx.x;
  const int lane = tid & 63, wv = tid >> 6;  // 16 waves; lane = sample p
  if (tid < MP_) s_c[tid] = concepts[g * MP_ + tid];
  __syncthreads();
  {
    const half4* p0 = (const half4*)rpart;
    const half4* p1 = p0 + (size_t)NP_ * 64;
#pragma unroll
    for (int i = 0; i < 4; ++i) {
      const int idx = tid + i * 1024, p = idx >> 6, c4 = idx & 63;
      const size_t off = (size_t)(g * MP_ + p) * 64 + c4;
      const float4 v0 = h2f(p0[off]);
      const float4 v1 = h2f(p1[off]);
      s_f[p][c4 * 4 + 0] = v0.x + v1.x;
      s_f[p][c4 * 4 + 1] = v0.y + v1.y;
      s_f[p][c4 * 4 + 2] = v0.z + v1.z;
      s_f[p][c4 * 4 + 3] = v0.w + v1.w;
    }
    const float4* ce4 = (const float4*)cemb;
    const float4 z = make_float4(0.f, 0.f, 0.f, 0.f);
    const int p = tid >> 4, k4 = tid & 15;
    const int c = s_c[p];
    const float4 q = c ? ce4[c * 16 + k4] : z;
    s_f[p][DV_ + k4 * 4 + 0] = q.x;
    s_f[p][DV_ + k4 * 4 + 1] = q.y;
    s_f[p][DV_ + k4 * 4 + 2] = q.z;
    s_f[p][DV_ + k4 * 4 + 3] = q.w;
  }
  __syncthreads();
  // ---- layer 1: h1[p][j] = relu(b1[j] + sum_k W1[j][k] f[p][k]) ----
  {
    const int j0 = __builtin_amdgcn_readfirstlane(wv * 4);  // FORCE scalar
    const float* W1r0 = W1 + (size_t)(j0 + 0) * 320;
    const float* W1r1 = W1 + (size_t)(j0 + 1) * 320;
    const float* W1r2 = W1 + (size_t)(j0 + 2) * 320;
    const float* W1r3 = W1 + (size_t)(j0 + 3) * 320;
    float a0 = b1[j0 + 0], a1 = b1[j0 + 1], a2 = b1[j0 + 2], a3 = b1[j0 + 3];
#pragma unroll 4
    for (int k4 = 0; k4 < 80; ++k4) {
      const float4 w0 = *(const float4*)(W1r0 + k4 * 4);  // s_load (uniform)
      const float4 w1 = *(const float4*)(W1r1 + k4 * 4);
      const float4 w2 = *(const float4*)(W1r2 + k4 * 4);
      const float4 w3 = *(const float4*)(W1r3 + k4 * 4);
      const float f0 = s_f[lane][k4 * 4 + 0];  // conflict-free b32
      const float f1 = s_f[lane][k4 * 4 + 1];
      const float f2 = s_f[lane][k4 * 4 + 2];
      const float f3 = s_f[lane][k4 * 4 + 3];
      a0 = fmaf(w0.x, f0, fmaf(w0.y, f1, fmaf(w0.z, f2, fmaf(w0.w, f3, a0))));
      a1 = fmaf(w1.x, f0, fmaf(w1.y, f1, fmaf(w1.z, f2, fmaf(w1.w, f3, a1))));
      a2 = fmaf(w2.x, f0, fmaf(w2.y, f1, fmaf(w2.z, f2, fmaf(w2.w, f3, a2))));
      a3 = fmaf(w3.x, f0, fmaf(w3.y, f1, fmaf(w3.z, f2, fmaf(w3.w, f3, a3))));
    }
    s_h1[lane][j0 + 0] = fmaxf(a0, 0.f);
    s_h1[lane][j0 + 1] = fmaxf(a1, 0.f);
    s_h1[lane][j0 + 2] = fmaxf(a2, 0.f);
    s_h1[lane][j0 + 3] = fmaxf(a3, 0.f);
  }
  __syncthreads();
  // ---- layer 2 + W3 partial: wave handles j2 = 4wv..4wv+3 ----
  {
    const int j0 = __builtin_amdgcn_readfirstlane(wv * 4);  // FORCE scalar
    const float* W2r0 = W2 + (size_t)(j0 + 0) * 64;
    const float* W2r1 = W2 + (size_t)(j0 + 1) * 64;
    const float* W2r2 = W2 + (size_t)(j0 + 2) * 64;
    const float* W2r3 = W2 + (size_t)(j0 + 3) * 64;
    float a0 = b2[j0 + 0], a1 = b2[j0 + 1], a2 = b2[j0 + 2], a3 = b2[j0 + 3];
#pragma unroll 4
    for (int k4 = 0; k4 < 16; ++k4) {
      const float4 w0 = *(const float4*)(W2r0 + k4 * 4);
      const float4 w1 = *(const float4*)(W2r1 + k4 * 4);
      const float4 w2 = *(const float4*)(W2r2 + k4 * 4);
      const float4 w3 = *(const float4*)(W2r3 + k4 * 4);
      const float h0 = s_h1[lane][k4 * 4 + 0];
      const float h1v = s_h1[lane][k4 * 4 + 1];
      const float h2v = s_h1[lane][k4 * 4 + 2];
      const float h3 = s_h1[lane][k4 * 4 + 3];
      a0 = fmaf(w0.x, h0, fmaf(w0.y, h1v, fmaf(w0.z, h2v, fmaf(w0.w, h3, a0))));
      a1 = fmaf(w1.x, h0, fmaf(w1.y, h1v, fmaf(w1.z, h2v, fmaf(w1.w, h3, a1))));
      a2 = fmaf(w2.x, h0, fmaf(w2.y, h1v, fmaf(w2.z, h2v, fmaf(w2.w, h3, a2))));
      a3 = fmaf(w3.x, h0, fmaf(w3.y, h1v, fmaf(w3.z, h2v, fmaf(w3.w, h3, a3))));
    }
    const float p3 = fmaxf(a0, 0.f) * W3[j0 + 0] + fmaxf(a1, 0.f) * W3[j0 + 1] +
                     fmaxf(a2, 0.f) * W3[j0 + 2] + fmaxf(a3, 0.f) * W3[j0 + 3];
    s_red[lane][wv] = p3;
  }
  __syncthreads();
  if (wv == 0) {
    float s = b3[0];
#pragma unroll
    for (int w = 0; w < 16; ++w) s += s_red[lane][w];
    out[g * MP_ + lane] = 1.f / (1.f + expf(-s));
  }
}

extern "C" void kernel_launch(void* const* d_in, const int* in_sizes, int n_in,
                              void* d_out, int out_size, void* d_ws, size_t ws_size,
                              hipStream_t stream) {
  const int* concepts = (const int*)d_in[0];
  const int* interactions = (const int*)d_in[1];
  const float* Kmem = (const float*)d_in[2];
  const float* Vmem = (const float*)d_in[3];
  const float* cemb = (const float*)d_in[4];
  const float* iemb = (const float*)d_in[5];
  const float* We = (const float*)d_in[6];
  const float* be = (const float*)d_in[7];
  const float* Wa = (const float*)d_in[8];
  const float* ba = (const float*)d_in[9];
  const float* W1 = (const float*)d_in[10];
  const float* b1 = (const float*)d_in[11];
  const float* W2 = (const float*)d_in[12];
  const float* b2 = (const float*)d_in[13];
  const float* W3 = (const float*)d_in[14];
  const float* b3 = (const float*)d_in[15];
  float* out = (float*)d_out;

  const size_t sz_w = (size_t)NCID * N_ * 4;
  const size_t sz_e = (size_t)NIID * DV_ * 4;
  float* wtab = (float*)d_ws;
  float* etab = (float*)((char*)d_ws + sz_w);
  float* atab = (float*)((char*)d_ws + sz_w + sz_e);
  u16* hmask = (u16*)((char*)d_ws + sz_w + 2 * sz_e);            // 8.2 KB
  h16* rpart = (h16*)((char*)d_ws + sz_w + 2 * sz_e + 16384);    // 2 x 64 MiB

  kW<<<dim3(NCID), dim3(512), 0, stream>>>(Kmem, cemb, wtab, hmask);
  kG<<<dim3((NIID + 7) / 8), dim3(512), 0, stream>>>(iemb, We, be, Wa, ba, etab, atab);
  kS<<<dim3(B_ * 2), dim3(1024), 0, stream>>>(concepts, interactions, Vmem,
                                              wtab, etab, atab, hmask, rpart);
  kM<<<dim3(NP_ / MP_), dim3(1024), 0, stream>>>(concepts, cemb, rpart,
                                                 W1, b1, W2, b2, W3, b3, out);
}

// Round 18
// 971.434 us; speedup vs baseline: 1.0703x; 1.0036x over previous
//
#include <hip/hip_runtime.h>

// DKVMN forward, round 32 — REVERT to R29 (session-best green, 966 us).
// R30 (row-granular skip: 828, regression) and R31 (hoisted reads: 805,
// regression) both failed to beat R29's kS (791). Three attempts bracketing
// the same structure confirm it's pinned: ~480 us VALU (hot-group FMAs at
// the proven 4-row skip granularity) + ~310 us structural barrier imbalance
// (slowest-of-16-waves per window, E[max]~1.5x mean). EPSW 1e-5 would push
// cold-row m-drift past the threshold margin -> numerics stay at 1e-6.
// This is R29 byte-exact; no variables changed.
//   kW: wtab[513][512] fp32 + hmask[513][8] u16   kG: etab/atab fp32
//   kS: ring-staged, s_racc dbuf, 1 barrier/4 steps, 4-group mask skip
//       (reads inside branch — compiler schedules them optimally).
//   kM: lane=p, readfirstlane-scalar weights, odd-stride b32 LDS.
// ws = 3.2 MB + 16 KB + 128 MiB.

#define B_ 256
#define T_ 512
#define N_ 512
#define DK_ 64
#define DV_ 256
#define S_ 64
#define NP_ (B_ * T_)
#define NCID 513
#define NIID 1025
#define EPSW 1e-6f

typedef _Float16 h16;
typedef __attribute__((ext_vector_type(4))) _Float16 half4;
typedef unsigned int u32;
typedef unsigned short u16;

__device__ __forceinline__ float dot4(float4 a, float4 b) {
  return a.x * b.x + a.y * b.y + a.z * b.z + a.w * b.w;
}
__device__ __forceinline__ float4 h2f(half4 h) {
  return make_float4((float)h.x, (float)h.y, (float)h.z, (float)h.w);
}
__device__ __forceinline__ half4 f2h(float4 f) {
  half4 h;
  h.x = (h16)f.x; h.y = (h16)f.y; h.z = (h16)f.z; h.w = (h16)f.w;
  return h;
}

// ============ kW: wtab[c][n] + hmask[c][wave], 513 blocks ==================
__global__ __launch_bounds__(512) void kW(const float* __restrict__ Kmem,
                                          const float* __restrict__ cemb,
                                          float* __restrict__ wtab,
                                          u16* __restrict__ hmask) {
  __shared__ float s_q[DK_];
  __shared__ float s_red[16];
  const int tid = threadIdx.x, c = blockIdx.x;
  if (tid < DK_) s_q[tid] = c ? cemb[c * DK_ + tid] : 0.f;
  __syncthreads();
  const int n = tid;
  const float4* kr = (const float4*)(Kmem + n * DK_);
  float acc = 0.f;
#pragma unroll
  for (int kk = 0; kk < DK_ / 4; ++kk) acc += dot4(kr[kk], *(const float4*)&s_q[kk * 4]);
  const int lane = tid & 63, wid = tid >> 6;
  float mx = acc;
  for (int off = 32; off; off >>= 1) mx = fmaxf(mx, __shfl_xor(mx, off, 64));
  if (lane == 0) s_red[wid] = mx;
  __syncthreads();
  float gmx = s_red[0];
#pragma unroll
  for (int i = 1; i < 8; ++i) gmx = fmaxf(gmx, s_red[i]);
  const float e = expf(acc - gmx);
  float sum = e;
  for (int off = 32; off; off >>= 1) sum += __shfl_xor(sum, off, 64);
  if (lane == 0) s_red[8 + wid] = sum;
  __syncthreads();
  float gs = 0.f;
#pragma unroll
  for (int i = 0; i < 8; ++i) gs += s_red[8 + i];
  const float w = e / gs;
  wtab[c * N_ + n] = w;
  // hot-group mask: bit i of hmask[c*8+wid] = OR over 4 rows of (w > EPSW).
  const unsigned long long bal = __ballot(w > EPSW);
  if (lane == 0) {
    u16 mm = 0;
#pragma unroll
    for (int i = 0; i < 16; ++i)
      if ((bal >> (4 * i)) & 0xFull) mm |= (u16)(1u << i);
    hmask[c * 8 + wid] = mm;
  }
}

// ============ kG: etab/atab[id][d], 129 blocks x 8 ids =====================
__global__ __launch_bounds__(512) void kG(const float* __restrict__ iemb,
                                          const float* __restrict__ We,
                                          const float* __restrict__ be,
                                          const float* __restrict__ Wa,
                                          const float* __restrict__ ba,
                                          float* __restrict__ etab,
                                          float* __restrict__ atab) {
  __shared__ float s_v[8 * DV_];
  const int tid = threadIdx.x, bi = blockIdx.x;
  {
    const int j = tid >> 6, c4 = tid & 63;
    const int id = bi * 8 + j;
    float4 v = make_float4(0.f, 0.f, 0.f, 0.f);
    if (id >= 1 && id < NIID) v = ((const float4*)iemb)[(size_t)id * 64 + c4];
    *(float4*)&s_v[j * DV_ + c4 * 4] = v;
  }
  __syncthreads();
  const int gate = tid >> 8, d = tid & 255;
  const float4* wr = (const float4*)((gate ? Wa : We) + d * DV_);
  float acc[8];
#pragma unroll
  for (int j = 0; j < 8; ++j) acc[j] = 0.f;
  for (int kk = 0; kk < DV_ / 4; ++kk) {
    const float4 w4 = wr[kk];
#pragma unroll
    for (int j = 0; j < 8; ++j) acc[j] += dot4(w4, *(const float4*)&s_v[j * DV_ + kk * 4]);
  }
  const float bias = gate ? ba[d] : be[d];
#pragma unroll
  for (int j = 0; j < 8; ++j) {
    const int id = bi * 8 + j;
    if (id < NIID) {
      if (gate) atab[(size_t)id * DV_ + d] = tanhf(acc[j] + bias);
      else      etab[(size_t)id * DV_ + d] = 1.f / (1.f + expf(-(acc[j] + bias)));
    }
  }
}

// ============ kS: ring-staged mask-driven recurrence, 512 x 1024 ===========
#define ROWOP(mr, wsel)                                   \
  do {                                                    \
    const float w_ = (wsel);                              \
    racc.x = fmaf(w_, mr.x, racc.x);                      \
    racc.y = fmaf(w_, mr.y, racc.y);                      \
    racc.z = fmaf(w_, mr.z, racc.z);                      \
    racc.w = fmaf(w_, mr.w, racc.w);                      \
    mr.x = fmaf(-w_, fmaf(e4.x, mr.x, -a4.x), mr.x);      \
    mr.y = fmaf(-w_, fmaf(e4.y, mr.y, -a4.y), mr.y);      \
    mr.z = fmaf(-w_, fmaf(e4.z, mr.z, -a4.z), mr.z);      \
    mr.w = fmaf(-w_, fmaf(e4.w, mr.w, -a4.w), mr.w);      \
  } while (0)

// guarded group: scalar bit test; w-row b128 read only when hot
#define GRPH(bitv, woff, A, B, C, D)                                      \
  if (nib & (bitv)) {                                                     \
    const float4 wq = *(const float4*)(wrow + (woff));                    \
    ROWOP(A, wq.x); ROWOP(B, wq.y); ROWOP(C, wq.z); ROWOP(D, wq.w);       \
  }

__global__ __launch_bounds__(1024)
__attribute__((amdgpu_waves_per_eu(4, 4))) void kS(
    const int* __restrict__ concepts, const int* __restrict__ inter,
    const float* __restrict__ Vmem, const float* __restrict__ wtab,
    const float* __restrict__ etab, const float* __restrict__ atab,
    const u16* __restrict__ hmask, h16* __restrict__ rpart) {
  __shared__ float s_w[8][DV_];            // 8 KB: ring of 8 t-rows
  __shared__ float s_e[8][DV_];            // 8 KB
  __shared__ float s_a[8][DV_];            // 8 KB
  __shared__ __align__(16) u16 s_mask[8][8];  // 128 B: hot-group masks
  __shared__ float s_racc[2][4][16][DV_];  // 128 KB: double-buffered windows
  const int tid = threadIdx.x, bx = blockIdx.x;
  const int b = bx >> 1, ch = bx & 1;
  const int lane = tid & 63, wv = tid >> 6;  // 16 waves
  const int row0 = ch * 256 + __builtin_amdgcn_readfirstlane(wv * 16);
  const int mword = ch * 4 + (wv >> 2);      // this wave's hmask u16 index
  const int mshift = (wv & 3) * 4;           // nibble position within it
  float4 m0, m1, m2, m3, m4, m5, m6, m7, m8, m9, m10, m11, m12, m13, m14, m15;
  {
    const float4* vm4 = (const float4*)Vmem + (size_t)row0 * 64 + lane;
    m0 = vm4[0 * 64];   m1 = vm4[1 * 64];   m2 = vm4[2 * 64];   m3 = vm4[3 * 64];
    m4 = vm4[4 * 64];   m5 = vm4[5 * 64];   m6 = vm4[6 * 64];   m7 = vm4[7 * 64];
    m8 = vm4[8 * 64];   m9 = vm4[9 * 64];   m10 = vm4[10 * 64]; m11 = vm4[11 * 64];
    m12 = vm4[12 * 64]; m13 = vm4[13 * 64]; m14 = vm4[14 * 64]; m15 = vm4[15 * 64];
  }
  const int* cb = concepts + b * T_;
  const int* ib = inter + b * T_;
  const float4* wtab4 = (const float4*)wtab;
  const float4* etab4 = (const float4*)etab;
  const float4* atab4 = (const float4*)atab;
  h16* rp = rpart + (size_t)ch * NP_ * DV_ + (size_t)b * T_ * DV_;

  // stage 4 t-rows (w/e/a + mask) into ring slots (tb..tb+3)&7; 768 threads.
  auto stage4 = [&](int tb, int toff) {
    const int idx = tid - toff;
    if (idx >= 0 && idx < 768) {
      const int r = idx / 192, q = idx % 192;
      const int arr = q >> 6, c4 = q & 63;
      const int t = tb + r, sl = t & 7;
      if (arr == 0) {
        *(float4*)&s_w[sl][c4 * 4] = wtab4[(size_t)cb[t] * 128 + ch * 64 + c4];
        if (q == 0)
          *(uint4*)&s_mask[sl][0] = *(const uint4*)(hmask + (size_t)cb[t] * 8);
      } else if (arr == 1) {
        *(float4*)&s_e[sl][c4 * 4] = etab4[(size_t)ib[t] * 64 + c4];
      } else {
        *(float4*)&s_a[sl][c4 * 4] = atab4[(size_t)ib[t] * 64 + c4];
      }
    }
  };

  stage4(0, 0);
  __syncthreads();

  for (int t0 = 0; t0 < T_; t0 += 4) {
    const int win = (t0 >> 2) & 1;
#pragma unroll 1  // CAP PRESSURE: one step's LDS reads live at a time
    for (int j = 0; j < 4; ++j) {
      const int sl = (t0 + j) & 7;
      const u32 nib =
          (__builtin_amdgcn_readfirstlane((u32)s_mask[sl][mword]) >> mshift) & 0xFu;
      float4 racc = make_float4(0.f, 0.f, 0.f, 0.f);
      if (nib) {
        const float4 e4 = *(const float4*)&s_e[sl][lane * 4];
        const float4 a4 = *(const float4*)&s_a[sl][lane * 4];
        const float* wrow = &s_w[sl][wv * 16];
        GRPH(1u, 0, m0, m1, m2, m3)
        GRPH(2u, 4, m4, m5, m6, m7)
        GRPH(4u, 8, m8, m9, m10, m11)
        GRPH(8u, 12, m12, m13, m14, m15)
      }
      *(float4*)&s_racc[win][j][wv][lane * 4] = racc;
    }
    if (t0 + 4 < T_) stage4(t0 + 4, 256);
    if (t0 > 0 && tid < 256) {
      const int j = tid >> 6, l = tid & 63;
      float4 acc = make_float4(0.f, 0.f, 0.f, 0.f);
#pragma unroll 4
      for (int w2 = 0; w2 < 16; ++w2) {
        const float4 v = *(const float4*)&s_racc[win ^ 1][j][w2][l * 4];
        acc.x += v.x; acc.y += v.y; acc.z += v.z; acc.w += v.w;
      }
      *(half4*)(rp + (size_t)(t0 - 4 + j) * DV_ + l * 4) = f2h(acc);
    }
    __syncthreads();
  }
  if (tid < 256) {
    const int buf = ((T_ - 4) >> 2) & 1;
    const int j = tid >> 6, l = tid & 63;
    float4 acc = make_float4(0.f, 0.f, 0.f, 0.f);
#pragma unroll 4
    for (int w2 = 0; w2 < 16; ++w2) {
      const float4 v = *(const float4*)&s_racc[buf][j][w2][l * 4];
      acc.x += v.x; acc.y += v.y; acc.z += v.z; acc.w += v.w;
    }
    *(half4*)(rp + (size_t)(T_ - 4 + j) * DV_ + l * 4) = f2h(acc);
  }
}

// ============ kM: MLP head, 2048 blocks x 1024 thr, lane=p (R28-exact) =====
#define MP_ 64
#define SF_ 321  // s_f dword stride (odd -> bank-conflict-free b32)
#define SH_ 65   // s_h1 dword stride (odd)
#define SR_ 17   // s_red dword stride (odd)
__global__ __launch_bounds__(1024)
__attribute__((amdgpu_waves_per_eu(4, 4))) void kM(
    const int* __restrict__ concepts, const float* __restrict__ cemb,
    const h16* __restrict__ rpart, const float* __restrict__ W1,
    const float* __restrict__ b1, const float* __restrict__ W2,
    const float* __restrict__ b2, const float* __restrict__ W3,
    const float* __restrict__ b3, float* __restrict__ out) {
  __shared__ float s_f[MP_][SF_];   // 82.2 KB: f = [r(256) | q(64)] fp32
  __shared__ float s_h1[MP_][SH_];  // 16.6 KB
  __shared__ float s_red[MP_][SR_]; // 4.4 KB
  __shared__ int s_c[MP_];
  const int tid = threadIdx.x, g = blockIdx.x;
  const int lane = tid & 63, wv = tid >> 6;  // 16 waves; lane = sample p
  if (tid < MP_) s_c[tid] = concepts[g * MP_ + tid];
  __syncthreads();
  {
    const half4* p0 = (const half4*)rpart;
    const half4* p1 = p0 + (size_t)NP_ * 64;
#pragma unroll
    for (int i = 0; i < 4; ++i) {
      const int idx = tid + i * 1024, p = idx >> 6, c4 = idx & 63;
      const size_t off = (size_t)(g * MP_ + p) * 64 + c4;
      const float4 v0 = h2f(p0[off]);
      const float4 v1 = h2f(p1[off]);
      s_f[p][c4 * 4 + 0] = v0.x + v1.x;
      s_f[p][c4 * 4 + 1] = v0.y + v1.y;
      s_f[p][c4 * 4 + 2] = v0.z + v1.z;
      s_f[p][c4 * 4 + 3] = v0.w + v1.w;
    }
    const float4* ce4 = (const float4*)cemb;
    const float4 z = make_float4(0.f, 0.f, 0.f, 0.f);
    const int p = tid >> 4, k4 = tid & 15;
    const int c = s_c[p];
    const float4 q = c ? ce4[c * 16 + k4] : z;
    s_f[p][DV_ + k4 * 4 + 0] = q.x;
    s_f[p][DV_ + k4 * 4 + 1] = q.y;
    s_f[p][DV_ + k4 * 4 + 2] = q.z;
    s_f[p][DV_ + k4 * 4 + 3] = q.w;
  }
  __syncthreads();
  // ---- layer 1: h1[p][j] = relu(b1[j] + sum_k W1[j][k] f[p][k]) ----
  {
    const int j0 = __builtin_amdgcn_readfirstlane(wv * 4);  // FORCE scalar
    const float* W1r0 = W1 + (size_t)(j0 + 0) * 320;
    const float* W1r1 = W1 + (size_t)(j0 + 1) * 320;
    const float* W1r2 = W1 + (size_t)(j0 + 2) * 320;
    const float* W1r3 = W1 + (size_t)(j0 + 3) * 320;
    float a0 = b1[j0 + 0], a1 = b1[j0 + 1], a2 = b1[j0 + 2], a3 = b1[j0 + 3];
#pragma unroll 4
    for (int k4 = 0; k4 < 80; ++k4) {
      const float4 w0 = *(const float4*)(W1r0 + k4 * 4);  // s_load (uniform)
      const float4 w1 = *(const float4*)(W1r1 + k4 * 4);
      const float4 w2 = *(const float4*)(W1r2 + k4 * 4);
      const float4 w3 = *(const float4*)(W1r3 + k4 * 4);
      const float f0 = s_f[lane][k4 * 4 + 0];  // conflict-free b32
      const float f1 = s_f[lane][k4 * 4 + 1];
      const float f2 = s_f[lane][k4 * 4 + 2];
      const float f3 = s_f[lane][k4 * 4 + 3];
      a0 = fmaf(w0.x, f0, fmaf(w0.y, f1, fmaf(w0.z, f2, fmaf(w0.w, f3, a0))));
      a1 = fmaf(w1.x, f0, fmaf(w1.y, f1, fmaf(w1.z, f2, fmaf(w1.w, f3, a1))));
      a2 = fmaf(w2.x, f0, fmaf(w2.y, f1, fmaf(w2.z, f2, fmaf(w2.w, f3, a2))));
      a3 = fmaf(w3.x, f0, fmaf(w3.y, f1, fmaf(w3.z, f2, fmaf(w3.w, f3, a3))));
    }
    s_h1[lane][j0 + 0] = fmaxf(a0, 0.f);
    s_h1[lane][j0 + 1] = fmaxf(a1, 0.f);
    s_h1[lane][j0 + 2] = fmaxf(a2, 0.f);
    s_h1[lane][j0 + 3] = fmaxf(a3, 0.f);
  }
  __syncthreads();
  // ---- layer 2 + W3 partial: wave handles j2 = 4wv..4wv+3 ----
  {
    const int j0 = __builtin_amdgcn_readfirstlane(wv * 4);  // FORCE scalar
    const float* W2r0 = W2 + (size_t)(j0 + 0) * 64;
    const float* W2r1 = W2 + (size_t)(j0 + 1) * 64;
    const float* W2r2 = W2 + (size_t)(j0 + 2) * 64;
    const float* W2r3 = W2 + (size_t)(j0 + 3) * 64;
    float a0 = b2[j0 + 0], a1 = b2[j0 + 1], a2 = b2[j0 + 2], a3 = b2[j0 + 3];
#pragma unroll 4
    for (int k4 = 0; k4 < 16; ++k4) {
      const float4 w0 = *(const float4*)(W2r0 + k4 * 4);
      const float4 w1 = *(const float4*)(W2r1 + k4 * 4);
      const float4 w2 = *(const float4*)(W2r2 + k4 * 4);
      const float4 w3 = *(const float4*)(W2r3 + k4 * 4);
      const float h0 = s_h1[lane][k4 * 4 + 0];
      const float h1v = s_h1[lane][k4 * 4 + 1];
      const float h2v = s_h1[lane][k4 * 4 + 2];
      const float h3 = s_h1[lane][k4 * 4 + 3];
      a0 = fmaf(w0.x, h0, fmaf(w0.y, h1v, fmaf(w0.z, h2v, fmaf(w0.w, h3, a0))));
      a1 = fmaf(w1.x, h0, fmaf(w1.y, h1v, fmaf(w1.z, h2v, fmaf(w1.w, h3, a1))));
      a2 = fmaf(w2.x, h0, fmaf(w2.y, h1v, fmaf(w2.z, h2v, fmaf(w2.w, h3, a2))));
      a3 = fmaf(w3.x, h0, fmaf(w3.y, h1v, fmaf(w3.z, h2v, fmaf(w3.w, h3, a3))));
    }
    const float p3 = fmaxf(a0, 0.f) * W3[j0 + 0] + fmaxf(a1, 0.f) * W3[j0 + 1] +
                     fmaxf(a2, 0.f) * W3[j0 + 2] + fmaxf(a3, 0.f) * W3[j0 + 3];
    s_red[lane][wv] = p3;
  }
  __syncthreads();
  if (wv == 0) {
    float s = b3[0];
#pragma unroll
    for (int w = 0; w < 16; ++w) s += s_red[lane][w];
    out[g * MP_ + lane] = 1.f / (1.f + expf(-s));
  }
}

extern "C" void kernel_launch(void* const* d_in, const int* in_sizes, int n_in,
                              void* d_out, int out_size, void* d_ws, size_t ws_size,
                              hipStream_t stream) {
  const int* concepts = (const int*)d_in[0];
  const int* interactions = (const int*)d_in[1];
  const float* Kmem = (const float*)d_in[2];
  const float* Vmem = (const float*)d_in[3];
  const float* cemb = (const float*)d_in[4];
  const float* iemb = (const float*)d_in[5];
  const float* We = (const float*)d_in[6];
  const float* be = (const float*)d_in[7];
  const float* Wa = (const float*)d_in[8];
  const float* ba = (const float*)d_in[9];
  const float* W1 = (const float*)d_in[10];
  const float* b1 = (const float*)d_in[11];
  const float* W2 = (const float*)d_in[12];
  const float* b2 = (const float*)d_in[13];
  const float* W3 = (const float*)d_in[14];
  const float* b3 = (const float*)d_in[15];
  float* out = (float*)d_out;

  const size_t sz_w = (size_t)NCID * N_ * 4;
  const size_t sz_e = (size_t)NIID * DV_ * 4;
  float* wtab = (float*)d_ws;
  float* etab = (float*)((char*)d_ws + sz_w);
  float* atab = (float*)((char*)d_ws + sz_w + sz_e);
  u16* hmask = (u16*)((char*)d_ws + sz_w + 2 * sz_e);            // 8.2 KB
  h16* rpart = (h16*)((char*)d_ws + sz_w + 2 * sz_e + 16384);    // 2 x 64 MiB

  kW<<<dim3(NCID), dim3(512), 0, stream>>>(Kmem, cemb, wtab, hmask);
  kG<<<dim3((NIID + 7) / 8), dim3(512), 0, stream>>>(iemb, We, be, Wa, ba, etab, atab);
  kS<<<dim3(B_ * 2), dim3(1024), 0, stream>>>(concepts, interactions, Vmem,
                                              wtab, etab, atab, hmask, rpart);
  kM<<<dim3(NP_ / MP_), dim3(1024), 0, stream>>>(concepts, cemb, rpart,
                                                 W1, b1, W2, b2, W3, b3, out);
}